// Round 1
// baseline (450.314 us; speedup 1.0000x reference)
//
#include <hip/hip_runtime.h>
#include <stdint.h>

#define NUMA 3
#define NUMC 80
#define NDET 1819440
#define NBOX 22743
#define HWT  7581
#define CAP  16384
#define KTOP 400
#define POST 100
#define NBIN1 2048
#define EQCAP 1024

__device__ __forceinline__ float sigmoidf_(float x) { return 1.0f / (1.0f + expf(-x)); }
__device__ __forceinline__ unsigned uminu(unsigned a, unsigned b) { return a < b ? a : b; }

// ---------------- init: zero hist + cut + counters -------------------------
__global__ void init_kernel(unsigned* __restrict__ p) {
    int i = blockIdx.x * blockDim.x + threadIdx.x;
    if (i < NBIN1 * 8 + 16) p[i] = 0;
}

// ---------------- decode (MODE 0: bbox + histogram, MODE 1: compact) -------
template <int MODE>
__global__ void decode_kernel(const float* __restrict__ tip0, const float* __restrict__ tip1,
                              const float* __restrict__ tip2,
                              const float* __restrict__ anc0, const float* __restrict__ anc1,
                              const float* __restrict__ anc2,
                              float* __restrict__ bboxW, unsigned* __restrict__ hist,
                              const unsigned* __restrict__ cutb,
                              unsigned* __restrict__ ccnt, unsigned* __restrict__ ckey,
                              unsigned* __restrict__ cidx)
{
    __shared__ unsigned lh[(MODE == 0) ? NBIN1 : 1];
    const int b   = blockIdx.y;
    const int t   = blockIdx.x * blockDim.x + threadIdx.x;
    if (MODE == 0) {
        for (int i = threadIdx.x; i < NBIN1; i += blockDim.x) lh[i] = 0;
        __syncthreads();
    }
    unsigned cutkey = 0;
    if (MODE == 1) cutkey = cutb[b] << 19;

    if (t < HWT) {
        int hwl, HW, W, boxOff, candOff;
        float strideF;
        const float* tip; const float* anc;
        if (t < 361)       { hwl = t;        HW = 361;  W = 19; strideF = 32.f; boxOff = 0;    candOff = 0;      tip = tip0; anc = anc0; }
        else if (t < 1805) { hwl = t - 361;  HW = 1444; W = 38; strideF = 16.f; boxOff = 1083; candOff = 86640;  tip = tip1; anc = anc1; }
        else               { hwl = t - 1805; HW = 5776; W = 76; strideF = 8.f;  boxOff = 5415; candOff = 433200; tip = tip2; anc = anc2; }
        const float* base_b = tip + (size_t)b * 255 * HW + hwl;
        float fx = (float)(hwl % W);
        float fy = (float)(hwl / W);
        for (int a = 0; a < NUMA; a++) {
            const float* p = base_b + (size_t)(a * 85) * HW;
            float tx = p[0];
            float ty = p[(size_t)HW];
            float tw = p[(size_t)2 * HW];
            float th = p[(size_t)3 * HW];
            float tc = p[(size_t)4 * HW];
            float conf = sigmoidf_(tc);
            int n = hwl * NUMA + a;
            if (MODE == 0) {
                float cx = (sigmoidf_(tx) + fx) * strideF;
                float cy = (sigmoidf_(ty) + fy) * strideF;
                float hw_ = expf(tw) * anc[2 * a]     * 0.5f;
                float hh_ = expf(th) * anc[2 * a + 1] * 0.5f;
                float* bo = bboxW + ((size_t)b * NBOX + boxOff + n) * 4;
                bo[0] = cx - hw_; bo[1] = cy - hh_; bo[2] = cx + hw_; bo[3] = cy + hh_;
            }
            for (int c = 0; c < NUMC; c++) {
                float sc = sigmoidf_(p[(size_t)(5 + c) * HW]) * conf;
                unsigned key = __float_as_uint(sc);
                if (MODE == 0) {
                    atomicAdd(&lh[key >> 19], 1u);
                } else {
                    if (key >= cutkey) {
                        unsigned pos = atomicAdd(&ccnt[b], 1u);
                        if (pos < CAP) {
                            ckey[(size_t)b * CAP + pos] = key;
                            cidx[(size_t)b * CAP + pos] = (unsigned)(candOff + n * NUMC + c);
                        }
                    }
                }
            }
        }
    }
    if (MODE == 0) {
        __syncthreads();
        for (int i = threadIdx.x; i < NBIN1; i += blockDim.x) {
            unsigned v = lh[i];
            if (v) atomicAdd(&hist[(size_t)b * NBIN1 + i], v);
        }
    }
}

// ---------------- find the rank-400 bin per image --------------------------
__global__ void findcut_kernel(const unsigned* __restrict__ hist, unsigned* __restrict__ cutb) {
    int i = threadIdx.x;
    if (i < 8) {
        unsigned cum = 0; int bin = 0;
        for (int bI = NBIN1 - 1; bI >= 0; bI--) {
            cum += hist[i * NBIN1 + bI];
            if (cum >= KTOP) { bin = bI; break; }
        }
        cutb[i] = (unsigned)bin;
    }
}

// ---------------- radix-select helper (block-wide) -------------------------
// rank is 1-based counted from the TOP (largest bin). Returns resv[0]=bin,
// resv[1]=rank within that bin (1-based).
__device__ void select_from_hist(unsigned* hist, int nbins, unsigned rank,
                                 unsigned* chunk, unsigned* resv, int tid, int T)
{
    int nch = nbins >> 6;
    for (int c = tid; c < nch; c += T) {
        unsigned s = 0;
        for (int k = 0; k < 64; k++) s += hist[(c << 6) + k];
        chunk[c] = s;
    }
    __syncthreads();
    if (tid == 0) {
        unsigned cum = 0; int c = nch - 1;
        for (; c > 0; c--) {
            if (cum + chunk[c] >= rank) break;
            cum += chunk[c];
        }
        int bin = (c << 6) + 63;
        for (; bin > (c << 6); bin--) {
            if (cum + hist[bin] >= rank) break;
            cum += hist[bin];
        }
        resv[0] = (unsigned)bin;
        resv[1] = rank - cum;
    }
    __syncthreads();
}

// ---------------- per-image: exact top-400, NMS, output --------------------
__global__ __launch_bounds__(512) void nms_kernel(const float* __restrict__ bboxW,
                                                  const unsigned* __restrict__ ckey,
                                                  const unsigned* __restrict__ cidx,
                                                  const unsigned* __restrict__ ccnt,
                                                  float* __restrict__ out)
{
    const int b = blockIdx.x;
    const int tid = threadIdx.x;
    const int T = 512;

    __shared__ unsigned hist[4096];
    __shared__ unsigned chunk[64];
    __shared__ unsigned resv[2];
    __shared__ unsigned selk[512], seli[512];
    __shared__ unsigned eqi[EQCAP];
    __shared__ float sx1[KTOP], sy1[KTOP], sx2[KTOP], sy2[KTOP], ssc[KTOP];
    __shared__ int   scid[KTOP];
    __shared__ unsigned long long maskS[KTOP * 7];
    __shared__ volatile unsigned long long vkeep[7];
    __shared__ unsigned cnts[2];
    __shared__ float oid[POST], osc[POST], obb[POST * 4];

    const unsigned n = uminu(ccnt[b], (unsigned)CAP);
    const unsigned* ck = ckey + (size_t)b * CAP;
    const unsigned* ci = cidx + (size_t)b * CAP;

    // ---- Round 1: bits [30:19] (2048 bins) ----
    for (int i = tid; i < NBIN1; i += T) hist[i] = 0;
    __syncthreads();
    for (unsigned i = tid; i < n; i += T) atomicAdd(&hist[ck[i] >> 19], 1u);
    __syncthreads();
    select_from_hist(hist, NBIN1, KTOP, chunk, resv, tid, T);
    unsigned b1 = resv[0], r2 = resv[1];
    __syncthreads();

    // ---- Round 2: bits [18:7] (4096 bins) among prefix b1 ----
    for (int i = tid; i < 4096; i += T) hist[i] = 0;
    __syncthreads();
    for (unsigned i = tid; i < n; i += T) {
        unsigned k = ck[i];
        if ((k >> 19) == b1) atomicAdd(&hist[(k >> 7) & 0xFFFu], 1u);
    }
    __syncthreads();
    select_from_hist(hist, 4096, r2, chunk, resv, tid, T);
    unsigned b2 = resv[0], r3 = resv[1];
    __syncthreads();

    // ---- Round 3: bits [6:0] (128 bins) among prefix (b1,b2) ----
    for (int i = tid; i < 128; i += T) hist[i] = 0;
    __syncthreads();
    unsigned pref = (b1 << 12) | b2;
    for (unsigned i = tid; i < n; i += T) {
        unsigned k = ck[i];
        if ((k >> 7) == pref) atomicAdd(&hist[k & 127u], 1u);
    }
    __syncthreads();
    select_from_hist(hist, 128, r3, chunk, resv, tid, T);
    unsigned b3 = resv[0], needEq = resv[1];
    unsigned K400 = (b1 << 19) | (b2 << 7) | b3;
    __syncthreads();

    // ---- compaction ----
    selk[tid] = 0u; seli[tid] = 0xFFFFFFFFu;
    for (int i = tid; i < EQCAP; i += T) eqi[i] = 0xFFFFFFFFu;
    if (tid == 0) { cnts[0] = 0; cnts[1] = 0; }
    __syncthreads();
    for (unsigned i = tid; i < n; i += T) {
        unsigned k = ck[i];
        if (k > K400) {
            unsigned p = atomicAdd(&cnts[0], 1u);
            if (p < KTOP) { selk[p] = k; seli[p] = ci[i]; }
        } else if (k == K400) {
            unsigned q = atomicAdd(&cnts[1], 1u);
            if (q < EQCAP) eqi[q] = ci[i];
        }
    }
    __syncthreads();
    unsigned selCnt = uminu(cnts[0], (unsigned)KTOP);

    // ---- sort tie list ascending by index, take smallest needEq ----
    for (int k2 = 2; k2 <= EQCAP; k2 <<= 1) {
        for (int j = k2 >> 1; j > 0; j >>= 1) {
            for (int i = tid; i < EQCAP; i += T) {
                int ixj = i ^ j;
                if (ixj > i) {
                    unsigned va = eqi[i], vb = eqi[ixj];
                    bool up = ((i & k2) == 0);
                    if (up ? (va > vb) : (va < vb)) { eqi[i] = vb; eqi[ixj] = va; }
                }
            }
            __syncthreads();
        }
    }
    for (unsigned t2 = tid; t2 < needEq; t2 += T) {
        unsigned p = selCnt + t2;
        if (p < KTOP) { selk[p] = K400; seli[p] = eqi[t2]; }
    }
    __syncthreads();

    // ---- bitonic sort 512 by (key desc, idx asc) == lax.top_k order ----
    for (int k2 = 2; k2 <= 512; k2 <<= 1) {
        for (int j = k2 >> 1; j > 0; j >>= 1) {
            int i = tid, ixj = i ^ j;
            if (ixj > i) {
                unsigned ka = selk[i], kb = selk[ixj], ia = seli[i], ib = seli[ixj];
                bool before = (ka > kb) || (ka == kb && ia < ib);
                bool up = ((i & k2) == 0);
                if (up ? !before : before) {
                    selk[i] = kb; selk[ixj] = ka; seli[i] = ib; seli[ixj] = ia;
                }
            }
            __syncthreads();
        }
    }

    // ---- gather detection rows ----
    if (tid < KTOP) {
        unsigned idx = seli[tid];
        int local, boxOff;
        if (idx < 86640u)       { local = (int)idx;           boxOff = 0;    }
        else if (idx < 433200u) { local = (int)(idx - 86640); boxOff = 1083; }
        else                    { local = (int)(idx - 433200); boxOff = 5415; }
        int cls = local % NUMC;
        int nn  = local / NUMC;
        const float* bo = bboxW + ((size_t)b * NBOX + boxOff + nn) * 4;
        sx1[tid] = bo[0]; sy1[tid] = bo[1]; sx2[tid] = bo[2]; sy2[tid] = bo[3];
        ssc[tid] = __uint_as_float(selk[tid]);
        scid[tid] = cls;
    }
    __syncthreads();

    // ---- suppression bitmasks: mask[i][w] bit b <=> j=w*64+b suppressible by i
    for (int p = tid; p < KTOP * 7; p += T) {
        int i = p / 7, w = p - i * 7;
        float x1i = sx1[i], y1i = sy1[i], x2i = sx2[i], y2i = sy2[i];
        float ai = fmaxf(x2i - x1i, 0.f) * fmaxf(y2i - y1i, 0.f);
        int cidI = scid[i];
        unsigned long long m = 0ull;
        int j0 = w * 64;
        int j1 = j0 + 64; if (j1 > KTOP) j1 = KTOP;
        int js = j0 > i + 1 ? j0 : i + 1;
        for (int j = js; j < j1; j++) {
            if (scid[j] != cidI) continue;
            float iw = fminf(x2i, sx2[j]) - fmaxf(x1i, sx1[j]);
            float ih = fminf(y2i, sy2[j]) - fmaxf(y1i, sy1[j]);
            iw = fmaxf(iw, 0.f); ih = fmaxf(ih, 0.f);
            float inter = iw * ih;
            float aj = fmaxf(sx2[j] - sx1[j], 0.f) * fmaxf(sy2[j] - sy1[j], 0.f);
            float iou = inter / (ai + aj - inter + 1e-12f);
            if (iou > 0.45f) m |= (1ull << (j - j0));
        }
        maskS[p] = m;
    }
    __syncthreads();

    // ---- greedy NMS (single wave, bitmask form of the reference fori_loop)
    if (tid < 64) {
        int lane = tid;
        if (lane < 7) vkeep[lane] = (lane == 6) ? 0xFFFFull : ~0ull;
        for (int i = 0; i < KTOP; i++) {
            unsigned long long kv = vkeep[i >> 6];
            if ((kv >> (i & 63)) & 1ull) {
                if (lane < 7) vkeep[lane] = vkeep[lane] & ~maskS[i * 7 + lane];
            }
        }
    }
    __syncthreads();

    // ---- emit top-100 (kept in sorted order), pad with -1 ----
    if (tid < POST) { oid[tid] = -1.f; osc[tid] = -1.f; }
    if (tid < POST * 4) obb[tid] = -1.f;
    __syncthreads();
    if (tid < KTOP) {
        int w = tid >> 6, bp = tid & 63;
        unsigned long long kw = vkeep[w];
        if ((kw >> bp) & 1ull) {
            int r = 0;
            for (int q = 0; q < w; q++) r += __popcll(vkeep[q]);
            r += __popcll(kw & ((1ull << bp) - 1ull));
            if (r < POST) {
                oid[r] = (float)scid[tid];
                osc[r] = ssc[tid];
                obb[r * 4 + 0] = sx1[tid];
                obb[r * 4 + 1] = sy1[tid];
                obb[r * 4 + 2] = sx2[tid];
                obb[r * 4 + 3] = sy2[tid];
            }
        }
    }
    __syncthreads();
    if (tid < POST) {
        out[b * POST + tid]       = oid[tid];
        out[800 + b * POST + tid] = osc[tid];
    }
    if (tid < POST * 4) out[1600 + b * POST * 4 + tid] = obb[tid];
}

// ---------------------------------------------------------------------------
extern "C" void kernel_launch(void* const* d_in, const int* in_sizes, int n_in,
                              void* d_out, int out_size, void* d_ws, size_t ws_size,
                              hipStream_t stream)
{
    const float* tip0 = (const float*)d_in[0];
    const float* tip1 = (const float*)d_in[1];
    const float* tip2 = (const float*)d_in[2];
    const float* anc0 = (const float*)d_in[3];
    const float* anc1 = (const float*)d_in[4];
    const float* anc2 = (const float*)d_in[5];
    float* out = (float*)d_out;

    // workspace layout (floats/u32, contiguous; ~4.03 MB total)
    float*    bboxW = (float*)d_ws;                       // 8*NBOX*4 f32
    unsigned* hist  = (unsigned*)(bboxW + (size_t)8 * NBOX * 4); // 8*2048 u32
    unsigned* cutb  = hist + 8 * NBIN1;                   // 8 u32
    unsigned* ccnt  = cutb + 8;                           // 8 u32
    unsigned* ckey  = ccnt + 8;                           // 8*CAP u32
    unsigned* cidx  = ckey + (size_t)8 * CAP;             // 8*CAP u32

    init_kernel<<<(NBIN1 * 8 + 16 + 255) / 256, 256, 0, stream>>>(hist);

    dim3 g((HWT + 255) / 256, 8);
    decode_kernel<0><<<g, 256, 0, stream>>>(tip0, tip1, tip2, anc0, anc1, anc2,
                                            bboxW, hist, cutb, ccnt, ckey, cidx);
    findcut_kernel<<<1, 64, 0, stream>>>(hist, cutb);
    decode_kernel<1><<<g, 256, 0, stream>>>(tip0, tip1, tip2, anc0, anc1, anc2,
                                            bboxW, hist, cutb, ccnt, ckey, cidx);
    nms_kernel<<<8, 512, 0, stream>>>(bboxW, ckey, cidx, ccnt, out);
}

// Round 2
// 331.915 us; speedup vs baseline: 1.3567x; 1.3567x over previous
//
#include <hip/hip_runtime.h>
#include <stdint.h>

#define NUMA 3
#define NUMC 80
#define NBOX 22743
#define CAP  16384
#define KTOP 400
#define POST 100
#define NBIN1 2048
#define EQCAP 1024

__device__ __forceinline__ float sigmoidf_(float x) { return 1.0f / (1.0f + expf(-x)); }
__device__ __forceinline__ unsigned uminu(unsigned a, unsigned b) { return a < b ? a : b; }

// ---------------- init: zero hist + cutb + ccnt ----------------------------
__global__ void init_kernel(unsigned* __restrict__ p) {
    int i = blockIdx.x * blockDim.x + threadIdx.x;
    if (i < NBIN1 * 8 + 16) p[i] = 0;
}

// ---------------- pass 1: fine-grained score histogram ---------------------
// grid (31, 3, 8): x = hw-chunk over {s0:2, s1:6, s2:23}, y = anchor, z = image
__global__ __launch_bounds__(256) void score_hist_kernel(
        const float* __restrict__ t0, const float* __restrict__ t1,
        const float* __restrict__ t2, unsigned* __restrict__ hist)
{
    __shared__ unsigned lh[NBIN1];
    for (int i = threadIdx.x; i < NBIN1; i += 256) lh[i] = 0;
    __syncthreads();

    const int b = blockIdx.z, a = blockIdx.y;
    const int bx = blockIdx.x;
    const float* tip; int HW, chunk;
    if (bx < 2)      { tip = t0; HW = 361;  chunk = bx; }
    else if (bx < 8) { tip = t1; HW = 1444; chunk = bx - 2; }
    else             { tip = t2; HW = 5776; chunk = bx - 8; }
    int hw = chunk * 256 + threadIdx.x;
    if (hw < HW) {
        const float* base = tip + (size_t)(b * 255 + a * 85) * HW + hw;
        float conf = sigmoidf_(base[(size_t)4 * HW]);
        #pragma unroll
        for (int c = 0; c < NUMC; c++) {
            float sc = sigmoidf_(base[(size_t)(5 + c) * HW]) * conf;
            atomicAdd(&lh[__float_as_uint(sc) >> 19], 1u);
        }
    }
    __syncthreads();
    unsigned* gh = hist + b * NBIN1;
    for (int i = threadIdx.x; i < NBIN1; i += 256) {
        unsigned v = lh[i];
        if (v) atomicAdd(&gh[i], v);
    }
}

// ---------------- find rank-400 bin per image ------------------------------
__global__ void findcut_kernel(const unsigned* __restrict__ hist, unsigned* __restrict__ cutb) {
    int i = threadIdx.x;
    if (i < 8) {
        unsigned cum = 0; int bin = 0;
        for (int bI = NBIN1 - 1; bI >= 0; bI--) {
            cum += hist[i * NBIN1 + bI];
            if (cum >= KTOP) { bin = bI; break; }
        }
        cutb[i] = (unsigned)bin;
    }
}

// ---------------- pass 2: fine-grained compaction --------------------------
__global__ __launch_bounds__(256) void score_compact_kernel(
        const float* __restrict__ t0, const float* __restrict__ t1,
        const float* __restrict__ t2,
        const unsigned* __restrict__ cutb, unsigned* __restrict__ ccnt,
        unsigned* __restrict__ ckey, unsigned* __restrict__ cidx)
{
    const int b = blockIdx.z, a = blockIdx.y;
    const int bx = blockIdx.x;
    const float* tip; int HW, chunk, candOff;
    if (bx < 2)      { tip = t0; HW = 361;  chunk = bx;     candOff = 0; }
    else if (bx < 8) { tip = t1; HW = 1444; chunk = bx - 2; candOff = 86640; }
    else             { tip = t2; HW = 5776; chunk = bx - 8; candOff = 433200; }
    int hw = chunk * 256 + threadIdx.x;
    if (hw >= HW) return;
    unsigned cutkey = cutb[b] << 19;
    const float* base = tip + (size_t)(b * 255 + a * 85) * HW + hw;
    float conf = sigmoidf_(base[(size_t)4 * HW]);
    int rowBase = candOff + (hw * NUMA + a) * NUMC;
    #pragma unroll
    for (int c = 0; c < NUMC; c++) {
        float sc = sigmoidf_(base[(size_t)(5 + c) * HW]) * conf;
        unsigned key = __float_as_uint(sc);
        if (key >= cutkey) {
            unsigned pos = atomicAdd(&ccnt[b], 1u);
            if (pos < CAP) {
                ckey[(size_t)b * CAP + pos] = key;
                cidx[(size_t)b * CAP + pos] = (unsigned)(rowBase + c);
            }
        }
    }
}

// ---------------- radix-select helper (block-wide) -------------------------
__device__ void select_from_hist(unsigned* hist, int nbins, unsigned rank,
                                 unsigned* chunk, unsigned* resv, int tid, int T)
{
    int nch = nbins >> 6;
    for (int c = tid; c < nch; c += T) {
        unsigned s = 0;
        for (int k = 0; k < 64; k++) s += hist[(c << 6) + k];
        chunk[c] = s;
    }
    __syncthreads();
    if (tid == 0) {
        unsigned cum = 0; int c = nch - 1;
        for (; c > 0; c--) {
            if (cum + chunk[c] >= rank) break;
            cum += chunk[c];
        }
        int bin = (c << 6) + 63;
        for (; bin > (c << 6); bin--) {
            if (cum + hist[bin] >= rank) break;
            cum += hist[bin];
        }
        resv[0] = (unsigned)bin;
        resv[1] = rank - cum;
    }
    __syncthreads();
}

// ---------------- per-image: exact top-400, NMS, output --------------------
__global__ __launch_bounds__(512) void nms_kernel(
        const float* __restrict__ t0, const float* __restrict__ t1,
        const float* __restrict__ t2,
        const float* __restrict__ anc0, const float* __restrict__ anc1,
        const float* __restrict__ anc2,
        const unsigned* __restrict__ ckey, const unsigned* __restrict__ cidx,
        const unsigned* __restrict__ ccnt, float* __restrict__ out)
{
    const int b = blockIdx.x;
    const int tid = threadIdx.x;
    const int T = 512;

    __shared__ unsigned hist[4096];
    __shared__ unsigned chunk[64];
    __shared__ unsigned resv[2];
    __shared__ unsigned selk[512], seli[512];
    __shared__ unsigned eqi[EQCAP];
    __shared__ float sx1[KTOP], sy1[KTOP], sx2[KTOP], sy2[KTOP], ssc[KTOP];
    __shared__ int   scid[KTOP];
    __shared__ unsigned long long maskS[KTOP * 7];
    __shared__ unsigned long long vkeep[7];
    __shared__ unsigned cnts[2];
    __shared__ float oid[POST], osc[POST], obb[POST * 4];

    const unsigned n = uminu(ccnt[b], (unsigned)CAP);
    const unsigned* ck = ckey + (size_t)b * CAP;
    const unsigned* ci = cidx + (size_t)b * CAP;

    // ---- Round 1: bits [30:19] ----
    for (int i = tid; i < NBIN1; i += T) hist[i] = 0;
    __syncthreads();
    for (unsigned i = tid; i < n; i += T) atomicAdd(&hist[ck[i] >> 19], 1u);
    __syncthreads();
    select_from_hist(hist, NBIN1, KTOP, chunk, resv, tid, T);
    unsigned b1 = resv[0], r2 = resv[1];
    __syncthreads();

    // ---- Round 2: bits [18:7] ----
    for (int i = tid; i < 4096; i += T) hist[i] = 0;
    __syncthreads();
    for (unsigned i = tid; i < n; i += T) {
        unsigned k = ck[i];
        if ((k >> 19) == b1) atomicAdd(&hist[(k >> 7) & 0xFFFu], 1u);
    }
    __syncthreads();
    select_from_hist(hist, 4096, r2, chunk, resv, tid, T);
    unsigned b2 = resv[0], r3 = resv[1];
    __syncthreads();

    // ---- Round 3: bits [6:0] ----
    for (int i = tid; i < 128; i += T) hist[i] = 0;
    __syncthreads();
    unsigned pref = (b1 << 12) | b2;
    for (unsigned i = tid; i < n; i += T) {
        unsigned k = ck[i];
        if ((k >> 7) == pref) atomicAdd(&hist[k & 127u], 1u);
    }
    __syncthreads();
    select_from_hist(hist, 128, r3, chunk, resv, tid, T);
    unsigned b3 = resv[0], needEq = resv[1];
    unsigned K400 = (b1 << 19) | (b2 << 7) | b3;
    __syncthreads();

    // ---- compaction ----
    selk[tid] = 0u; seli[tid] = 0xFFFFFFFFu;
    for (int i = tid; i < EQCAP; i += T) eqi[i] = 0xFFFFFFFFu;
    if (tid == 0) { cnts[0] = 0; cnts[1] = 0; }
    __syncthreads();
    for (unsigned i = tid; i < n; i += T) {
        unsigned k = ck[i];
        if (k > K400) {
            unsigned p = atomicAdd(&cnts[0], 1u);
            if (p < KTOP) { selk[p] = k; seli[p] = ci[i]; }
        } else if (k == K400) {
            unsigned q = atomicAdd(&cnts[1], 1u);
            if (q < EQCAP) eqi[q] = ci[i];
        }
    }
    __syncthreads();
    unsigned selCnt = uminu(cnts[0], (unsigned)KTOP);
    unsigned eqN   = uminu(cnts[1], (unsigned)EQCAP);

    // ---- tie list: only sort if we must pick a strict subset ----
    if (eqN > needEq) {
        int P2 = 1; while ((unsigned)P2 < eqN) P2 <<= 1;
        for (int k2 = 2; k2 <= P2; k2 <<= 1) {
            for (int j = k2 >> 1; j > 0; j >>= 1) {
                __syncthreads();
                for (int i = tid; i < P2; i += T) {
                    int ixj = i ^ j;
                    if (ixj > i && ixj < P2) {
                        unsigned va = eqi[i], vb = eqi[ixj];
                        bool up = ((i & k2) == 0);
                        if (up ? (va > vb) : (va < vb)) { eqi[i] = vb; eqi[ixj] = va; }
                    }
                }
            }
        }
        __syncthreads();
    }
    for (unsigned t2 = tid; t2 < needEq; t2 += T) {
        unsigned p = selCnt + t2;
        if (p < KTOP) { selk[p] = K400; seli[p] = eqi[t2]; }
    }
    __syncthreads();

    // ---- bitonic sort 512 by (key desc, idx asc); j<64 passes are in-wave --
    for (int k2 = 2; k2 <= 512; k2 <<= 1) {
        int j = k2 >> 1;
        for (; j >= 64; j >>= 1) {
            __syncthreads();
            int i = tid, ixj = i ^ j;
            if (ixj > i) {
                unsigned ka = selk[i], kb = selk[ixj], ia = seli[i], ib = seli[ixj];
                bool before = (ka > kb) || (ka == kb && ia < ib);
                bool up = ((i & k2) == 0);
                if (up ? !before : before) {
                    selk[i] = kb; selk[ixj] = ka; seli[i] = ib; seli[ixj] = ia;
                }
            }
        }
        __syncthreads();
        for (; j > 0; j >>= 1) {
            int i = tid, ixj = i ^ j;
            if (ixj > i) {
                unsigned ka = selk[i], kb = selk[ixj], ia = seli[i], ib = seli[ixj];
                bool before = (ka > kb) || (ka == kb && ia < ib);
                bool up = ((i & k2) == 0);
                if (up ? !before : before) {
                    selk[i] = kb; selk[ixj] = ka; seli[i] = ib; seli[ixj] = ia;
                }
            }
        }
    }
    __syncthreads();

    // ---- gather + on-the-fly box decode for the 400 selected ----
    if (tid < KTOP) {
        unsigned idx = seli[tid];
        const float* tip; const float* anc; int HW, W, candOff; float strideF;
        if (idx < 86640u)       { tip = t0; anc = anc0; HW = 361;  W = 19; strideF = 32.f; candOff = 0; }
        else if (idx < 433200u) { tip = t1; anc = anc1; HW = 1444; W = 38; strideF = 16.f; candOff = 86640; }
        else                    { tip = t2; anc = anc2; HW = 5776; W = 76; strideF = 8.f;  candOff = 433200; }
        unsigned local = idx - (unsigned)candOff;
        int cls = (int)(local % NUMC);
        int nn  = (int)(local / NUMC);
        int a = nn % NUMA, hwl = nn / NUMA;
        const float* base = tip + (size_t)(b * 255 + a * 85) * HW + hwl;
        float tx = base[0];
        float ty = base[(size_t)HW];
        float tw = base[(size_t)2 * HW];
        float th = base[(size_t)3 * HW];
        float fx = (float)(hwl % W), fy = (float)(hwl / W);
        float cx = (sigmoidf_(tx) + fx) * strideF;
        float cy = (sigmoidf_(ty) + fy) * strideF;
        float hw_ = expf(tw) * anc[2 * a]     * 0.5f;
        float hh_ = expf(th) * anc[2 * a + 1] * 0.5f;
        sx1[tid] = cx - hw_; sy1[tid] = cy - hh_;
        sx2[tid] = cx + hw_; sy2[tid] = cy + hh_;
        ssc[tid] = __uint_as_float(selk[tid]);
        scid[tid] = cls;
    }
    __syncthreads();

    // ---- suppression bitmasks ----
    for (int p = tid; p < KTOP * 7; p += T) {
        int i = p / 7, w = p - i * 7;
        float x1i = sx1[i], y1i = sy1[i], x2i = sx2[i], y2i = sy2[i];
        float ai = fmaxf(x2i - x1i, 0.f) * fmaxf(y2i - y1i, 0.f);
        int cidI = scid[i];
        unsigned long long m = 0ull;
        int j0 = w * 64;
        int j1 = j0 + 64; if (j1 > KTOP) j1 = KTOP;
        int js = j0 > i + 1 ? j0 : i + 1;
        for (int j = js; j < j1; j++) {
            if (scid[j] != cidI) continue;
            float iw = fminf(x2i, sx2[j]) - fmaxf(x1i, sx1[j]);
            float ih = fminf(y2i, sy2[j]) - fmaxf(y1i, sy1[j]);
            iw = fmaxf(iw, 0.f); ih = fmaxf(ih, 0.f);
            float inter = iw * ih;
            float aj = fmaxf(sx2[j] - sx1[j], 0.f) * fmaxf(sy2[j] - sy1[j], 0.f);
            float iou = inter / (ai + aj - inter + 1e-12f);
            if (iou > 0.45f) m |= (1ull << (j - j0));
        }
        maskS[p] = m;
    }
    __syncthreads();

    // ---- greedy NMS: keep words in lanes 0..6, uniform-lane shfl broadcast
    if (tid < 64) {
        unsigned long long keep = 0ull;
        if (tid < 7) keep = (tid == 6) ? 0xFFFFull : ~0ull;
        unsigned long long m = (tid < 7) ? maskS[tid] : 0ull;  // prefetch i=0
        for (int i = 0; i < KTOP; i++) {
            unsigned long long mn = (tid < 7 && i + 1 < KTOP) ? maskS[(i + 1) * 7 + tid] : 0ull;
            int w = i >> 6;  // wave-uniform -> v_readlane
            unsigned klo = (unsigned)__shfl((int)(unsigned)(keep & 0xFFFFFFFFull), w);
            unsigned khi = (unsigned)__shfl((int)(unsigned)(keep >> 32), w);
            unsigned long long kw = ((unsigned long long)khi << 32) | klo;
            if ((kw >> (i & 63)) & 1ull) keep &= ~m;
            m = mn;
        }
        if (tid < 7) vkeep[tid] = keep;
    }
    __syncthreads();

    // ---- emit top-100, pad -1 ----
    if (tid < POST) { oid[tid] = -1.f; osc[tid] = -1.f; }
    if (tid < POST * 4) obb[tid] = -1.f;
    __syncthreads();
    if (tid < KTOP) {
        int w = tid >> 6, bp = tid & 63;
        unsigned long long kw = vkeep[w];
        if ((kw >> bp) & 1ull) {
            int r = 0;
            for (int q = 0; q < w; q++) r += __popcll(vkeep[q]);
            r += __popcll(kw & ((1ull << bp) - 1ull));
            if (r < POST) {
                oid[r] = (float)scid[tid];
                osc[r] = ssc[tid];
                obb[r * 4 + 0] = sx1[tid];
                obb[r * 4 + 1] = sy1[tid];
                obb[r * 4 + 2] = sx2[tid];
                obb[r * 4 + 3] = sy2[tid];
            }
        }
    }
    __syncthreads();
    if (tid < POST) {
        out[b * POST + tid]       = oid[tid];
        out[800 + b * POST + tid] = osc[tid];
    }
    if (tid < POST * 4) out[1600 + b * POST * 4 + tid] = obb[tid];
}

// ---------------------------------------------------------------------------
extern "C" void kernel_launch(void* const* d_in, const int* in_sizes, int n_in,
                              void* d_out, int out_size, void* d_ws, size_t ws_size,
                              hipStream_t stream)
{
    const float* tip0 = (const float*)d_in[0];
    const float* tip1 = (const float*)d_in[1];
    const float* tip2 = (const float*)d_in[2];
    const float* anc0 = (const float*)d_in[3];
    const float* anc1 = (const float*)d_in[4];
    const float* anc2 = (const float*)d_in[5];
    float* out = (float*)d_out;

    // workspace: hist(8*2048) | cutb(8) | ccnt(8) | ckey(8*CAP) | cidx(8*CAP)
    unsigned* hist = (unsigned*)d_ws;
    unsigned* cutb = hist + 8 * NBIN1;
    unsigned* ccnt = cutb + 8;
    unsigned* ckey = ccnt + 8;
    unsigned* cidx = ckey + (size_t)8 * CAP;

    init_kernel<<<(NBIN1 * 8 + 16 + 255) / 256, 256, 0, stream>>>(hist);

    dim3 g(31, 3, 8);
    score_hist_kernel<<<g, 256, 0, stream>>>(tip0, tip1, tip2, hist);
    findcut_kernel<<<1, 64, 0, stream>>>(hist, cutb);
    score_compact_kernel<<<g, 256, 0, stream>>>(tip0, tip1, tip2, cutb, ccnt, ckey, cidx);
    nms_kernel<<<8, 512, 0, stream>>>(tip0, tip1, tip2, anc0, anc1, anc2,
                                      ckey, cidx, ccnt, out);
}

// Round 3
// 307.156 us; speedup vs baseline: 1.4661x; 1.0806x over previous
//
#include <hip/hip_runtime.h>
#include <stdint.h>

#define NUMA 3
#define NUMC 80
#define CAP  16384
#define KTOP 400
#define POST 100
#define NBIN1 2048
#define EQCAP 1024

__device__ __forceinline__ float sigmoidf_(float x) { return 1.0f / (1.0f + expf(-x)); }
__device__ __forceinline__ unsigned uminu(unsigned a, unsigned b) { return a < b ? a : b; }

// ---------------- init: zero hist + cutb + ccnt ----------------------------
__global__ void init_kernel(unsigned* __restrict__ p) {
    int i = blockIdx.x * blockDim.x + threadIdx.x;
    if (i < NBIN1 * 8 + 16) p[i] = 0;
}

// ---------------- score emit helper ----------------------------------------
template <int MODE>
__device__ __forceinline__ void emit_score(float sc, unsigned idx, unsigned cutkey,
        unsigned* lh, int b, unsigned* ccnt, unsigned* ckey, unsigned* cidx)
{
    unsigned key = __float_as_uint(sc);
    if (MODE == 0) {
        atomicAdd(&lh[key >> 19], 1u);
    } else {
        if (key >= cutkey) {
            unsigned pos = atomicAdd(&ccnt[b], 1u);
            if (pos < CAP) {
                ckey[(size_t)b * CAP + pos] = key;
                cidx[(size_t)b * CAP + pos] = idx;
            }
        }
    }
}

// ---------------- decode passes --------------------------------------------
// grid (36, 3, 8): x = (scale-block sb [0..8]) * 4 + channel-group cg [0..3],
// y = anchor, z = image. sb==0 -> t0 scalar; sb 1..2 -> t1 float4 chunks;
// sb 3..8 -> t2 float4 chunks. Each block covers 20 classes.
template <int MODE>
__global__ __launch_bounds__(256) void decode_pass(
        const float* __restrict__ t0, const float* __restrict__ t1,
        const float* __restrict__ t2,
        unsigned* __restrict__ hist, const unsigned* __restrict__ cutb,
        unsigned* __restrict__ ccnt, unsigned* __restrict__ ckey,
        unsigned* __restrict__ cidx)
{
    __shared__ unsigned lh[(MODE == 0) ? NBIN1 : 1];
    const int tid = threadIdx.x;
    if (MODE == 0) {
        for (int i = tid; i < NBIN1; i += 256) lh[i] = 0;
        __syncthreads();
    }
    const int b = blockIdx.z, a = blockIdx.y;
    const int bx = blockIdx.x;
    const int cg = bx & 3;
    const int sb = bx >> 2;
    const int c0 = cg * 20;

    unsigned cutkey = 0;
    if (MODE == 1) cutkey = cutb[b] << 19;

    if (sb == 0) {
        // ---- t0: HW=361 (stride not 16B-aligned) -> scalar, 2 cells/thread
        const float* base = t0 + (size_t)(b * 255 + a * 85) * 361;
        const int hw0 = tid, hw1 = tid + 256;
        const bool v1 = hw1 < 361;
        float cf0 = sigmoidf_(base[4 * 361 + hw0]);
        float cf1 = v1 ? sigmoidf_(base[4 * 361 + hw1]) : 0.f;
        #pragma unroll 5
        for (int c = 0; c < 20; c++) {
            const float* pl = base + (size_t)(5 + c0 + c) * 361;
            float x0 = pl[hw0];
            float x1 = v1 ? pl[hw1] : 0.f;
            emit_score<MODE>(sigmoidf_(x0) * cf0,
                             (unsigned)((hw0 * NUMA + a) * NUMC + c0 + c),
                             cutkey, lh, b, ccnt, ckey, cidx);
            if (v1)
                emit_score<MODE>(sigmoidf_(x1) * cf1,
                                 (unsigned)((hw1 * NUMA + a) * NUMC + c0 + c),
                                 cutkey, lh, b, ccnt, ckey, cidx);
        }
    } else {
        // ---- t1/t2: float4 (plane strides 1444/5776 floats are 16B-multiples)
        const float* tip; int vecHW, chunk, candOff;
        if (sb <= 2) { tip = t1; vecHW = 361;  chunk = sb - 1; candOff = 86640; }
        else         { tip = t2; vecHW = 1444; chunk = sb - 3; candOff = 433200; }
        int vlane = chunk * 256 + tid;
        if (vlane < vecHW) {
            const float4* basev = (const float4*)(tip + (size_t)(b * 255 + a * 85) * (size_t)(vecHW * 4)) + vlane;
            float4 cv = basev[(size_t)4 * vecHW];
            float cf0 = sigmoidf_(cv.x), cf1 = sigmoidf_(cv.y);
            float cf2 = sigmoidf_(cv.z), cf3 = sigmoidf_(cv.w);
            unsigned ib0 = (unsigned)(candOff + (vlane * 4 * NUMA + a) * NUMC + c0);
            #pragma unroll 5
            for (int c = 0; c < 20; c++) {
                float4 s = basev[(size_t)(5 + c0 + c) * vecHW];
                unsigned ib = ib0 + (unsigned)c;
                emit_score<MODE>(sigmoidf_(s.x) * cf0, ib,       cutkey, lh, b, ccnt, ckey, cidx);
                emit_score<MODE>(sigmoidf_(s.y) * cf1, ib + 240, cutkey, lh, b, ccnt, ckey, cidx);
                emit_score<MODE>(sigmoidf_(s.z) * cf2, ib + 480, cutkey, lh, b, ccnt, ckey, cidx);
                emit_score<MODE>(sigmoidf_(s.w) * cf3, ib + 720, cutkey, lh, b, ccnt, ckey, cidx);
            }
        }
    }

    if (MODE == 0) {
        __syncthreads();
        unsigned* gh = hist + b * NBIN1;
        for (int i = tid; i < NBIN1; i += 256) {
            unsigned v = lh[i];
            if (v) atomicAdd(&gh[i], v);
        }
    }
}

// ---------------- find rank-400 bin per image (LDS-staged) -----------------
__global__ __launch_bounds__(256) void findcut_kernel(const unsigned* __restrict__ hist,
                                                      unsigned* __restrict__ cutb) {
    __shared__ unsigned h[NBIN1];
    int b = blockIdx.x;
    for (int i = threadIdx.x; i < NBIN1; i += 256) h[i] = hist[b * NBIN1 + i];
    __syncthreads();
    if (threadIdx.x == 0) {
        unsigned cum = 0; int bin = 0;
        for (int i = NBIN1 - 1; i >= 0; i--) {
            cum += h[i];
            if (cum >= KTOP) { bin = i; break; }
        }
        cutb[b] = (unsigned)bin;
    }
}

// ---------------- radix-select helper (block-wide) -------------------------
__device__ void select_from_hist(unsigned* hist, int nbins, unsigned rank,
                                 unsigned* chunk, unsigned* resv, int tid, int T)
{
    int nch = nbins >> 6;
    for (int c = tid; c < nch; c += T) {
        unsigned s = 0;
        for (int k = 0; k < 64; k++) s += hist[(c << 6) + k];
        chunk[c] = s;
    }
    __syncthreads();
    if (tid == 0) {
        unsigned cum = 0; int c = nch - 1;
        for (; c > 0; c--) {
            if (cum + chunk[c] >= rank) break;
            cum += chunk[c];
        }
        int bin = (c << 6) + 63;
        for (; bin > (c << 6); bin--) {
            if (cum + hist[bin] >= rank) break;
            cum += hist[bin];
        }
        resv[0] = (unsigned)bin;
        resv[1] = rank - cum;
    }
    __syncthreads();
}

// ---------------- per-image: exact top-400, NMS, output --------------------
__global__ __launch_bounds__(512) void nms_kernel(
        const float* __restrict__ t0, const float* __restrict__ t1,
        const float* __restrict__ t2,
        const float* __restrict__ anc0, const float* __restrict__ anc1,
        const float* __restrict__ anc2,
        const unsigned* __restrict__ ckey, const unsigned* __restrict__ cidx,
        const unsigned* __restrict__ ccnt, float* __restrict__ out)
{
    const int b = blockIdx.x;
    const int tid = threadIdx.x;
    const int T = 512;

    __shared__ unsigned hist[4096];
    __shared__ unsigned chunk[64];
    __shared__ unsigned resv[2];
    __shared__ unsigned selk[512], seli[512];
    __shared__ unsigned eqi[EQCAP];
    __shared__ float sx1[KTOP], sy1[KTOP], sx2[KTOP], sy2[KTOP], ssc[KTOP];
    __shared__ int   scid[KTOP];
    __shared__ unsigned long long maskS[KTOP * 7];
    __shared__ unsigned long long vkeep[7];
    __shared__ unsigned cnts[2];
    __shared__ float oid[POST], osc[POST], obb[POST * 4];

    const unsigned n = uminu(ccnt[b], (unsigned)CAP);
    const unsigned* ck = ckey + (size_t)b * CAP;
    const unsigned* ci = cidx + (size_t)b * CAP;

    // ---- Round 1: bits [30:19] ----
    for (int i = tid; i < NBIN1; i += T) hist[i] = 0;
    __syncthreads();
    for (unsigned i = tid; i < n; i += T) atomicAdd(&hist[ck[i] >> 19], 1u);
    __syncthreads();
    select_from_hist(hist, NBIN1, KTOP, chunk, resv, tid, T);
    unsigned b1 = resv[0], r2 = resv[1];
    __syncthreads();

    // ---- Round 2: bits [18:7] ----
    for (int i = tid; i < 4096; i += T) hist[i] = 0;
    __syncthreads();
    for (unsigned i = tid; i < n; i += T) {
        unsigned k = ck[i];
        if ((k >> 19) == b1) atomicAdd(&hist[(k >> 7) & 0xFFFu], 1u);
    }
    __syncthreads();
    select_from_hist(hist, 4096, r2, chunk, resv, tid, T);
    unsigned b2 = resv[0], r3 = resv[1];
    __syncthreads();

    // ---- Round 3: bits [6:0] ----
    for (int i = tid; i < 128; i += T) hist[i] = 0;
    __syncthreads();
    unsigned pref = (b1 << 12) | b2;
    for (unsigned i = tid; i < n; i += T) {
        unsigned k = ck[i];
        if ((k >> 7) == pref) atomicAdd(&hist[k & 127u], 1u);
    }
    __syncthreads();
    select_from_hist(hist, 128, r3, chunk, resv, tid, T);
    unsigned b3 = resv[0], needEq = resv[1];
    unsigned K400 = (b1 << 19) | (b2 << 7) | b3;
    __syncthreads();

    // ---- compaction ----
    selk[tid] = 0u; seli[tid] = 0xFFFFFFFFu;
    for (int i = tid; i < EQCAP; i += T) eqi[i] = 0xFFFFFFFFu;
    if (tid == 0) { cnts[0] = 0; cnts[1] = 0; }
    __syncthreads();
    for (unsigned i = tid; i < n; i += T) {
        unsigned k = ck[i];
        if (k > K400) {
            unsigned p = atomicAdd(&cnts[0], 1u);
            if (p < KTOP) { selk[p] = k; seli[p] = ci[i]; }
        } else if (k == K400) {
            unsigned q = atomicAdd(&cnts[1], 1u);
            if (q < EQCAP) eqi[q] = ci[i];
        }
    }
    __syncthreads();
    unsigned selCnt = uminu(cnts[0], (unsigned)KTOP);
    unsigned eqN   = uminu(cnts[1], (unsigned)EQCAP);

    // ---- tie list: only sort if we must pick a strict subset ----
    if (eqN > needEq) {
        int P2 = 1; while ((unsigned)P2 < eqN) P2 <<= 1;
        for (int k2 = 2; k2 <= P2; k2 <<= 1) {
            for (int j = k2 >> 1; j > 0; j >>= 1) {
                __syncthreads();
                for (int i = tid; i < P2; i += T) {
                    int ixj = i ^ j;
                    if (ixj > i && ixj < P2) {
                        unsigned va = eqi[i], vb = eqi[ixj];
                        bool up = ((i & k2) == 0);
                        if (up ? (va > vb) : (va < vb)) { eqi[i] = vb; eqi[ixj] = va; }
                    }
                }
            }
        }
        __syncthreads();
    }
    for (unsigned t2v = tid; t2v < needEq; t2v += T) {
        unsigned p = selCnt + t2v;
        if (p < KTOP) { selk[p] = K400; seli[p] = eqi[t2v]; }
    }
    __syncthreads();

    // ---- bitonic sort 512 by (key desc, idx asc); j<64 passes in-wave ----
    for (int k2 = 2; k2 <= 512; k2 <<= 1) {
        int j = k2 >> 1;
        for (; j >= 64; j >>= 1) {
            __syncthreads();
            int i = tid, ixj = i ^ j;
            if (ixj > i) {
                unsigned ka = selk[i], kb = selk[ixj], ia = seli[i], ib = seli[ixj];
                bool before = (ka > kb) || (ka == kb && ia < ib);
                bool up = ((i & k2) == 0);
                if (up ? !before : before) {
                    selk[i] = kb; selk[ixj] = ka; seli[i] = ib; seli[ixj] = ia;
                }
            }
        }
        __syncthreads();
        for (; j > 0; j >>= 1) {
            int i = tid, ixj = i ^ j;
            if (ixj > i) {
                unsigned ka = selk[i], kb = selk[ixj], ia = seli[i], ib = seli[ixj];
                bool before = (ka > kb) || (ka == kb && ia < ib);
                bool up = ((i & k2) == 0);
                if (up ? !before : before) {
                    selk[i] = kb; selk[ixj] = ka; seli[i] = ib; seli[ixj] = ia;
                }
            }
        }
    }
    __syncthreads();

    // ---- gather + on-the-fly box decode for the 400 selected ----
    if (tid < KTOP) {
        unsigned idx = seli[tid];
        const float* tip; const float* anc; int HW, W, candOff; float strideF;
        if (idx < 86640u)       { tip = t0; anc = anc0; HW = 361;  W = 19; strideF = 32.f; candOff = 0; }
        else if (idx < 433200u) { tip = t1; anc = anc1; HW = 1444; W = 38; strideF = 16.f; candOff = 86640; }
        else                    { tip = t2; anc = anc2; HW = 5776; W = 76; strideF = 8.f;  candOff = 433200; }
        unsigned local = idx - (unsigned)candOff;
        int cls = (int)(local % NUMC);
        int nn  = (int)(local / NUMC);
        int a = nn % NUMA, hwl = nn / NUMA;
        const float* base = tip + (size_t)(b * 255 + a * 85) * HW + hwl;
        float tx = base[0];
        float ty = base[(size_t)HW];
        float tw = base[(size_t)2 * HW];
        float th = base[(size_t)3 * HW];
        float fx = (float)(hwl % W), fy = (float)(hwl / W);
        float cx = (sigmoidf_(tx) + fx) * strideF;
        float cy = (sigmoidf_(ty) + fy) * strideF;
        float hw_ = expf(tw) * anc[2 * a]     * 0.5f;
        float hh_ = expf(th) * anc[2 * a + 1] * 0.5f;
        sx1[tid] = cx - hw_; sy1[tid] = cy - hh_;
        sx2[tid] = cx + hw_; sy2[tid] = cy + hh_;
        ssc[tid] = __uint_as_float(selk[tid]);
        scid[tid] = cls;
    }
    __syncthreads();

    // ---- suppression bitmasks ----
    for (int p = tid; p < KTOP * 7; p += T) {
        int i = p / 7, w = p - i * 7;
        float x1i = sx1[i], y1i = sy1[i], x2i = sx2[i], y2i = sy2[i];
        float ai = fmaxf(x2i - x1i, 0.f) * fmaxf(y2i - y1i, 0.f);
        int cidI = scid[i];
        unsigned long long m = 0ull;
        int j0 = w * 64;
        int j1 = j0 + 64; if (j1 > KTOP) j1 = KTOP;
        int js = j0 > i + 1 ? j0 : i + 1;
        for (int j = js; j < j1; j++) {
            if (scid[j] != cidI) continue;
            float iw = fminf(x2i, sx2[j]) - fmaxf(x1i, sx1[j]);
            float ih = fminf(y2i, sy2[j]) - fmaxf(y1i, sy1[j]);
            iw = fmaxf(iw, 0.f); ih = fmaxf(ih, 0.f);
            float inter = iw * ih;
            float aj = fmaxf(sx2[j] - sx1[j], 0.f) * fmaxf(sy2[j] - sy1[j], 0.f);
            float iou = inter / (ai + aj - inter + 1e-12f);
            if (iou > 0.45f) m |= (1ull << (j - j0));
        }
        maskS[p] = m;
    }
    __syncthreads();

    // ---- greedy NMS: keep words in lanes 0..6, uniform-lane shfl broadcast
    if (tid < 64) {
        unsigned long long keep = 0ull;
        if (tid < 7) keep = (tid == 6) ? 0xFFFFull : ~0ull;
        unsigned long long m = (tid < 7) ? maskS[tid] : 0ull;  // prefetch i=0
        for (int i = 0; i < KTOP; i++) {
            unsigned long long mn = (tid < 7 && i + 1 < KTOP) ? maskS[(i + 1) * 7 + tid] : 0ull;
            int w = i >> 6;  // wave-uniform -> v_readlane
            unsigned klo = (unsigned)__shfl((int)(unsigned)(keep & 0xFFFFFFFFull), w);
            unsigned khi = (unsigned)__shfl((int)(unsigned)(keep >> 32), w);
            unsigned long long kw = ((unsigned long long)khi << 32) | klo;
            if ((kw >> (i & 63)) & 1ull) keep &= ~m;
            m = mn;
        }
        if (tid < 7) vkeep[tid] = keep;
    }
    __syncthreads();

    // ---- emit top-100, pad -1 ----
    if (tid < POST) { oid[tid] = -1.f; osc[tid] = -1.f; }
    if (tid < POST * 4) obb[tid] = -1.f;
    __syncthreads();
    if (tid < KTOP) {
        int w = tid >> 6, bp = tid & 63;
        unsigned long long kw = vkeep[w];
        if ((kw >> bp) & 1ull) {
            int r = 0;
            for (int q = 0; q < w; q++) r += __popcll(vkeep[q]);
            r += __popcll(kw & ((1ull << bp) - 1ull));
            if (r < POST) {
                oid[r] = (float)scid[tid];
                osc[r] = ssc[tid];
                obb[r * 4 + 0] = sx1[tid];
                obb[r * 4 + 1] = sy1[tid];
                obb[r * 4 + 2] = sx2[tid];
                obb[r * 4 + 3] = sy2[tid];
            }
        }
    }
    __syncthreads();
    if (tid < POST) {
        out[b * POST + tid]       = oid[tid];
        out[800 + b * POST + tid] = osc[tid];
    }
    if (tid < POST * 4) out[1600 + b * POST * 4 + tid] = obb[tid];
}

// ---------------------------------------------------------------------------
extern "C" void kernel_launch(void* const* d_in, const int* in_sizes, int n_in,
                              void* d_out, int out_size, void* d_ws, size_t ws_size,
                              hipStream_t stream)
{
    const float* tip0 = (const float*)d_in[0];
    const float* tip1 = (const float*)d_in[1];
    const float* tip2 = (const float*)d_in[2];
    const float* anc0 = (const float*)d_in[3];
    const float* anc1 = (const float*)d_in[4];
    const float* anc2 = (const float*)d_in[5];
    float* out = (float*)d_out;

    // workspace: hist(8*2048) | cutb(8) | ccnt(8) | ckey(8*CAP) | cidx(8*CAP)
    unsigned* hist = (unsigned*)d_ws;
    unsigned* cutb = hist + 8 * NBIN1;
    unsigned* ccnt = cutb + 8;
    unsigned* ckey = ccnt + 8;
    unsigned* cidx = ckey + (size_t)8 * CAP;

    init_kernel<<<(NBIN1 * 8 + 16 + 255) / 256, 256, 0, stream>>>(hist);

    dim3 g(36, 3, 8);
    decode_pass<0><<<g, 256, 0, stream>>>(tip0, tip1, tip2, hist, cutb, ccnt, ckey, cidx);
    findcut_kernel<<<8, 256, 0, stream>>>(hist, cutb);
    decode_pass<1><<<g, 256, 0, stream>>>(tip0, tip1, tip2, hist, cutb, ccnt, ckey, cidx);
    nms_kernel<<<8, 512, 0, stream>>>(tip0, tip1, tip2, anc0, anc1, anc2,
                                      ckey, cidx, ccnt, out);
}

// Round 4
// 288.399 us; speedup vs baseline: 1.5614x; 1.0650x over previous
//
#include <hip/hip_runtime.h>
#include <stdint.h>

#define NUMA 3
#define NUMC 80
#define CAP  16384
#define KTOP 400
#define POST 100
#define NBIN1 2048
#define EQCAP 1024

__device__ __forceinline__ float sigmoidf_(float x) { return 1.0f / (1.0f + expf(-x)); }
__device__ __forceinline__ unsigned uminu(unsigned a, unsigned b) { return a < b ? a : b; }

// ---------------- init: zero hist + cutb + ccnt ----------------------------
__global__ void init_kernel(unsigned* __restrict__ p) {
    int i = blockIdx.x * blockDim.x + threadIdx.x;
    if (i < NBIN1 * 8 + 16) p[i] = 0;
}

// ---------------- score emit helper ----------------------------------------
template <int MODE>
__device__ __forceinline__ void emit_score(float sc, unsigned idx, unsigned cutkey,
        unsigned* lh, int b, unsigned* ccnt, unsigned* ckey, unsigned* cidx)
{
    unsigned key = __float_as_uint(sc);
    if (MODE == 0) {
        atomicAdd(&lh[key >> 19], 1u);
    } else {
        if (key >= cutkey) {
            unsigned pos = atomicAdd(&ccnt[b], 1u);
            if (pos < CAP) {
                ckey[(size_t)b * CAP + pos] = key;
                cidx[(size_t)b * CAP + pos] = idx;
            }
        }
    }
}

// ---------------- decode passes --------------------------------------------
// grid (72, 3, 8): x = sb*8 + cg  (sb: 0 -> t0 scalar, 1..2 -> t1 float4,
// 3..8 -> t2 float4; cg: 8 groups of 10 classes), y = anchor, z = image.
// Loads are batched into register arrays with a sched barrier so ~11-22
// global loads stay in flight per wave (MLP, not load width, was the wall).
template <int MODE>
__global__ __launch_bounds__(256, 4) void decode_pass(
        const float* __restrict__ t0, const float* __restrict__ t1,
        const float* __restrict__ t2,
        unsigned* __restrict__ hist, const unsigned* __restrict__ cutb,
        unsigned* __restrict__ ccnt, unsigned* __restrict__ ckey,
        unsigned* __restrict__ cidx)
{
    __shared__ unsigned lh[(MODE == 0) ? NBIN1 : 1];
    const int tid = threadIdx.x;
    if (MODE == 0) {
        for (int i = tid; i < NBIN1; i += 256) lh[i] = 0;
        __syncthreads();
    }
    const int b = blockIdx.z, a = blockIdx.y;
    const int bx = blockIdx.x;
    const int cg = bx & 7;
    const int sb = bx >> 3;
    const int c0 = cg * 10;

    unsigned cutkey = 0;
    if (MODE == 1) cutkey = cutb[b] << 19;

    if (sb == 0) {
        // ---- t0: HW=361 (plane stride not 16B-aligned) -> scalar, 2 cells/thread
        const float* base = t0 + (size_t)(b * 255 + a * 85) * 361;
        const int hw0 = tid, hw1 = tid + 256;
        const bool v1 = hw1 < 361;
        float cr0 = base[4 * 361 + hw0];
        float cr1 = v1 ? base[4 * 361 + hw1] : 0.f;
        float x0[10], x1[10];
        #pragma unroll
        for (int u = 0; u < 10; u++) {
            const float* pl = base + (size_t)(5 + c0 + u) * 361;
            x0[u] = pl[hw0];
            x1[u] = v1 ? pl[hw1] : 0.f;
        }
        __builtin_amdgcn_sched_barrier(0);
        float cf0 = sigmoidf_(cr0);
        float cf1 = sigmoidf_(cr1);
        #pragma unroll
        for (int u = 0; u < 10; u++) {
            emit_score<MODE>(sigmoidf_(x0[u]) * cf0,
                             (unsigned)((hw0 * NUMA + a) * NUMC + c0 + u),
                             cutkey, lh, b, ccnt, ckey, cidx);
            if (v1)
                emit_score<MODE>(sigmoidf_(x1[u]) * cf1,
                                 (unsigned)((hw1 * NUMA + a) * NUMC + c0 + u),
                                 cutkey, lh, b, ccnt, ckey, cidx);
        }
    } else {
        // ---- t1/t2: float4 (plane strides 1444/5776 floats = 16B multiples)
        const float* tip; int vecHW, chunk, candOff;
        if (sb <= 2) { tip = t1; vecHW = 361;  chunk = sb - 1; candOff = 86640; }
        else         { tip = t2; vecHW = 1444; chunk = sb - 3; candOff = 433200; }
        int vlane = chunk * 256 + tid;
        if (vlane < vecHW) {
            const float4* basev = (const float4*)(tip + (size_t)(b * 255 + a * 85) * (size_t)(vecHW * 4)) + vlane;
            float4 cv = basev[(size_t)4 * vecHW];
            float4 s[10];
            #pragma unroll
            for (int u = 0; u < 10; u++) s[u] = basev[(size_t)(5 + c0 + u) * vecHW];
            __builtin_amdgcn_sched_barrier(0);
            float cf0 = sigmoidf_(cv.x), cf1 = sigmoidf_(cv.y);
            float cf2 = sigmoidf_(cv.z), cf3 = sigmoidf_(cv.w);
            unsigned ib0 = (unsigned)(candOff + (vlane * 4 * NUMA + a) * NUMC + c0);
            #pragma unroll
            for (int u = 0; u < 10; u++) {
                unsigned ib = ib0 + (unsigned)u;
                emit_score<MODE>(sigmoidf_(s[u].x) * cf0, ib,       cutkey, lh, b, ccnt, ckey, cidx);
                emit_score<MODE>(sigmoidf_(s[u].y) * cf1, ib + 240, cutkey, lh, b, ccnt, ckey, cidx);
                emit_score<MODE>(sigmoidf_(s[u].z) * cf2, ib + 480, cutkey, lh, b, ccnt, ckey, cidx);
                emit_score<MODE>(sigmoidf_(s[u].w) * cf3, ib + 720, cutkey, lh, b, ccnt, ckey, cidx);
            }
        }
    }

    if (MODE == 0) {
        __syncthreads();
        unsigned* gh = hist + b * NBIN1;
        for (int i = tid; i < NBIN1; i += 256) {
            unsigned v = lh[i];
            if (v) atomicAdd(&gh[i], v);
        }
    }
}

// ---------------- wave-parallel rank select over an LDS histogram ----------
// Finds bin s.t. count(bins > bin) < rank <= count(bins >= bin), counting
// from the TOP. resv[0]=bin, resv[1]=rank within bin (1-based). Wave 0 only;
// caller must __syncthreads() after.
__device__ __forceinline__ void wave_select(const unsigned* h, int nbins, unsigned rank,
                                            unsigned* resv, int tid)
{
    if (tid >= 64) return;
    const int lane = tid;
    const int cs = nbins >> 6;
    // per-chunk sums, swizzled reads (max 2-way bank alias)
    unsigned v = 0;
    for (int k = 0; k < cs; k++) {
        int off = (k + lane) & (cs - 1);
        v += h[lane * cs + off];
    }
    // suffix sum across lanes: S_l = sum_{j>=l} v_j
    unsigned S = v;
    #pragma unroll
    for (int o = 1; o < 64; o <<= 1) {
        unsigned t = (unsigned)__shfl_down((int)S, o);
        if (lane + o < 64) S += t;
    }
    unsigned long long bm = __ballot(S >= rank);
    int C = 63 - __builtin_clzll(bm);            // crossing chunk
    unsigned SC = (unsigned)__builtin_amdgcn_readlane((int)S, C);
    unsigned vC = (unsigned)__builtin_amdgcn_readlane((int)v, C);
    unsigned rem = rank - (SC - vC);             // rank within chunk, from top
    // within chunk C (cs <= 64 bins)
    unsigned w = (lane < cs) ? h[C * cs + lane] : 0u;
    unsigned T = w;
    #pragma unroll
    for (int o = 1; o < 64; o <<= 1) {
        unsigned t = (unsigned)__shfl_down((int)T, o);
        if (lane + o < 64) T += t;
    }
    unsigned long long bm2 = __ballot((T >= rem) && (lane < cs));
    int B = 63 - __builtin_clzll(bm2);           // crossing bin within chunk
    unsigned TB = (unsigned)__builtin_amdgcn_readlane((int)T, B);
    unsigned wB = (unsigned)__builtin_amdgcn_readlane((int)w, B);
    if (lane == 0) {
        resv[0] = (unsigned)(C * cs + B);
        resv[1] = rem - (TB - wB);
    }
}

// ---------------- find rank-400 bin per image ------------------------------
__global__ __launch_bounds__(256) void findcut_kernel(const unsigned* __restrict__ hist,
                                                      unsigned* __restrict__ cutb) {
    __shared__ unsigned h[NBIN1];
    __shared__ unsigned resv[2];
    int b = blockIdx.x;
    for (int i = threadIdx.x; i < NBIN1; i += 256) h[i] = hist[b * NBIN1 + i];
    __syncthreads();
    wave_select(h, NBIN1, KTOP, resv, threadIdx.x);
    __syncthreads();
    if (threadIdx.x == 0) cutb[b] = resv[0];
}

// ---------------- per-image: exact top-400, NMS, output --------------------
__global__ __launch_bounds__(512) void nms_kernel(
        const float* __restrict__ t0, const float* __restrict__ t1,
        const float* __restrict__ t2,
        const float* __restrict__ anc0, const float* __restrict__ anc1,
        const float* __restrict__ anc2,
        const unsigned* __restrict__ ckey, const unsigned* __restrict__ cidx,
        const unsigned* __restrict__ ccnt, float* __restrict__ out)
{
    const int b = blockIdx.x;
    const int tid = threadIdx.x;
    const int T = 512;

    __shared__ unsigned hist[4096];
    __shared__ unsigned resv[2];
    __shared__ unsigned selk[512], seli[512];
    __shared__ unsigned eqi[EQCAP];
    __shared__ float sx1[KTOP], sy1[KTOP], sx2[KTOP], sy2[KTOP], ssc[KTOP];
    __shared__ int   scid[KTOP];
    __shared__ unsigned long long maskS[KTOP * 7];
    __shared__ unsigned long long vkeep[7];
    __shared__ unsigned cnts[2];
    __shared__ float oid[POST], osc[POST], obb[POST * 4];

    const unsigned n = uminu(ccnt[b], (unsigned)CAP);
    const unsigned* ck = ckey + (size_t)b * CAP;
    const unsigned* ci = cidx + (size_t)b * CAP;

    // ---- Round 1: bits [30:19] ----
    for (int i = tid; i < NBIN1; i += T) hist[i] = 0;
    __syncthreads();
    for (unsigned i = tid; i < n; i += T) atomicAdd(&hist[ck[i] >> 19], 1u);
    __syncthreads();
    wave_select(hist, NBIN1, KTOP, resv, tid);
    __syncthreads();
    unsigned b1 = resv[0], r2 = resv[1];
    __syncthreads();

    // ---- Round 2: bits [18:7] ----
    for (int i = tid; i < 4096; i += T) hist[i] = 0;
    __syncthreads();
    for (unsigned i = tid; i < n; i += T) {
        unsigned k = ck[i];
        if ((k >> 19) == b1) atomicAdd(&hist[(k >> 7) & 0xFFFu], 1u);
    }
    __syncthreads();
    wave_select(hist, 4096, r2, resv, tid);
    __syncthreads();
    unsigned b2 = resv[0], r3 = resv[1];
    __syncthreads();

    // ---- Round 3: bits [6:0] ----
    for (int i = tid; i < 128; i += T) hist[i] = 0;
    __syncthreads();
    unsigned pref = (b1 << 12) | b2;
    for (unsigned i = tid; i < n; i += T) {
        unsigned k = ck[i];
        if ((k >> 7) == pref) atomicAdd(&hist[k & 127u], 1u);
    }
    __syncthreads();
    wave_select(hist, 128, r3, resv, tid);
    __syncthreads();
    unsigned b3 = resv[0], needEq = resv[1];
    unsigned K400 = (b1 << 19) | (b2 << 7) | b3;
    __syncthreads();

    // ---- compaction ----
    selk[tid] = 0u; seli[tid] = 0xFFFFFFFFu;
    for (int i = tid; i < EQCAP; i += T) eqi[i] = 0xFFFFFFFFu;
    if (tid == 0) { cnts[0] = 0; cnts[1] = 0; }
    __syncthreads();
    for (unsigned i = tid; i < n; i += T) {
        unsigned k = ck[i];
        if (k > K400) {
            unsigned p = atomicAdd(&cnts[0], 1u);
            if (p < KTOP) { selk[p] = k; seli[p] = ci[i]; }
        } else if (k == K400) {
            unsigned q = atomicAdd(&cnts[1], 1u);
            if (q < EQCAP) eqi[q] = ci[i];
        }
    }
    __syncthreads();
    unsigned selCnt = uminu(cnts[0], (unsigned)KTOP);
    unsigned eqN   = uminu(cnts[1], (unsigned)EQCAP);

    // ---- tie list: only sort if we must pick a strict subset ----
    if (eqN > needEq) {
        int P2 = 1; while ((unsigned)P2 < eqN) P2 <<= 1;
        for (int k2 = 2; k2 <= P2; k2 <<= 1) {
            for (int j = k2 >> 1; j > 0; j >>= 1) {
                __syncthreads();
                for (int i = tid; i < P2; i += T) {
                    int ixj = i ^ j;
                    if (ixj > i && ixj < P2) {
                        unsigned va = eqi[i], vb = eqi[ixj];
                        bool up = ((i & k2) == 0);
                        if (up ? (va > vb) : (va < vb)) { eqi[i] = vb; eqi[ixj] = va; }
                    }
                }
            }
        }
        __syncthreads();
    }
    for (unsigned t2v = tid; t2v < needEq; t2v += T) {
        unsigned p = selCnt + t2v;
        if (p < KTOP) { selk[p] = K400; seli[p] = eqi[t2v]; }
    }
    __syncthreads();

    // ---- bitonic sort 512 by (key desc, idx asc); j<64 passes in-wave ----
    for (int k2 = 2; k2 <= 512; k2 <<= 1) {
        int j = k2 >> 1;
        for (; j >= 64; j >>= 1) {
            __syncthreads();
            int i = tid, ixj = i ^ j;
            if (ixj > i) {
                unsigned ka = selk[i], kb = selk[ixj], ia = seli[i], ib = seli[ixj];
                bool before = (ka > kb) || (ka == kb && ia < ib);
                bool up = ((i & k2) == 0);
                if (up ? !before : before) {
                    selk[i] = kb; selk[ixj] = ka; seli[i] = ib; seli[ixj] = ia;
                }
            }
        }
        __syncthreads();
        for (; j > 0; j >>= 1) {
            int i = tid, ixj = i ^ j;
            if (ixj > i) {
                unsigned ka = selk[i], kb = selk[ixj], ia = seli[i], ib = seli[ixj];
                bool before = (ka > kb) || (ka == kb && ia < ib);
                bool up = ((i & k2) == 0);
                if (up ? !before : before) {
                    selk[i] = kb; selk[ixj] = ka; seli[i] = ib; seli[ixj] = ia;
                }
            }
        }
    }
    __syncthreads();

    // ---- gather + on-the-fly box decode for the 400 selected ----
    if (tid < KTOP) {
        unsigned idx = seli[tid];
        const float* tip; const float* anc; int HW, W, candOff; float strideF;
        if (idx < 86640u)       { tip = t0; anc = anc0; HW = 361;  W = 19; strideF = 32.f; candOff = 0; }
        else if (idx < 433200u) { tip = t1; anc = anc1; HW = 1444; W = 38; strideF = 16.f; candOff = 86640; }
        else                    { tip = t2; anc = anc2; HW = 5776; W = 76; strideF = 8.f;  candOff = 433200; }
        unsigned local = idx - (unsigned)candOff;
        int cls = (int)(local % NUMC);
        int nn  = (int)(local / NUMC);
        int a = nn % NUMA, hwl = nn / NUMA;
        const float* base = tip + (size_t)(b * 255 + a * 85) * HW + hwl;
        float tx = base[0];
        float ty = base[(size_t)HW];
        float tw = base[(size_t)2 * HW];
        float th = base[(size_t)3 * HW];
        float fx = (float)(hwl % W), fy = (float)(hwl / W);
        float cx = (sigmoidf_(tx) + fx) * strideF;
        float cy = (sigmoidf_(ty) + fy) * strideF;
        float hw_ = expf(tw) * anc[2 * a]     * 0.5f;
        float hh_ = expf(th) * anc[2 * a + 1] * 0.5f;
        sx1[tid] = cx - hw_; sy1[tid] = cy - hh_;
        sx2[tid] = cx + hw_; sy2[tid] = cy + hh_;
        ssc[tid] = __uint_as_float(selk[tid]);
        scid[tid] = cls;
    }
    __syncthreads();

    // ---- suppression bitmasks ----
    for (int p = tid; p < KTOP * 7; p += T) {
        int i = p / 7, w = p - i * 7;
        float x1i = sx1[i], y1i = sy1[i], x2i = sx2[i], y2i = sy2[i];
        float ai = fmaxf(x2i - x1i, 0.f) * fmaxf(y2i - y1i, 0.f);
        int cidI = scid[i];
        unsigned long long m = 0ull;
        int j0 = w * 64;
        int j1 = j0 + 64; if (j1 > KTOP) j1 = KTOP;
        int js = j0 > i + 1 ? j0 : i + 1;
        for (int j = js; j < j1; j++) {
            if (scid[j] != cidI) continue;
            float iw = fminf(x2i, sx2[j]) - fmaxf(x1i, sx1[j]);
            float ih = fminf(y2i, sy2[j]) - fmaxf(y1i, sy1[j]);
            iw = fmaxf(iw, 0.f); ih = fmaxf(ih, 0.f);
            float inter = iw * ih;
            float aj = fmaxf(sx2[j] - sx1[j], 0.f) * fmaxf(sy2[j] - sy1[j], 0.f);
            float iou = inter / (ai + aj - inter + 1e-12f);
            if (iou > 0.45f) m |= (1ull << (j - j0));
        }
        maskS[p] = m;
    }
    __syncthreads();

    // ---- greedy NMS: keep words in lanes 0..6; v_readlane broadcast -------
    if (tid < 64) {
        unsigned long long keep = 0ull;
        if (tid < 7) keep = (tid == 6) ? 0xFFFFull : ~0ull;
        unsigned long long m = (tid < 7) ? maskS[tid] : 0ull;  // prefetch i=0
        for (int i = 0; i < KTOP; i++) {
            unsigned long long mn = (tid < 7 && i + 1 < KTOP) ? maskS[(i + 1) * 7 + tid] : 0ull;
            int w = i >> 6;  // wave-uniform
            unsigned klo = (unsigned)__builtin_amdgcn_readlane((int)(unsigned)(keep & 0xFFFFFFFFull), w);
            unsigned khi = (unsigned)__builtin_amdgcn_readlane((int)(unsigned)(keep >> 32), w);
            unsigned long long kw = ((unsigned long long)khi << 32) | klo;
            if ((kw >> (i & 63)) & 1ull) keep &= ~m;
            m = mn;
        }
        if (tid < 7) vkeep[tid] = keep;
    }
    __syncthreads();

    // ---- emit top-100, pad -1 ----
    if (tid < POST) { oid[tid] = -1.f; osc[tid] = -1.f; }
    if (tid < POST * 4) obb[tid] = -1.f;
    __syncthreads();
    if (tid < KTOP) {
        int w = tid >> 6, bp = tid & 63;
        unsigned long long kw = vkeep[w];
        if ((kw >> bp) & 1ull) {
            int r = 0;
            for (int q = 0; q < w; q++) r += __popcll(vkeep[q]);
            r += __popcll(kw & ((1ull << bp) - 1ull));
            if (r < POST) {
                oid[r] = (float)scid[tid];
                osc[r] = ssc[tid];
                obb[r * 4 + 0] = sx1[tid];
                obb[r * 4 + 1] = sy1[tid];
                obb[r * 4 + 2] = sx2[tid];
                obb[r * 4 + 3] = sy2[tid];
            }
        }
    }
    __syncthreads();
    if (tid < POST) {
        out[b * POST + tid]       = oid[tid];
        out[800 + b * POST + tid] = osc[tid];
    }
    if (tid < POST * 4) out[1600 + b * POST * 4 + tid] = obb[tid];
}

// ---------------------------------------------------------------------------
extern "C" void kernel_launch(void* const* d_in, const int* in_sizes, int n_in,
                              void* d_out, int out_size, void* d_ws, size_t ws_size,
                              hipStream_t stream)
{
    const float* tip0 = (const float*)d_in[0];
    const float* tip1 = (const float*)d_in[1];
    const float* tip2 = (const float*)d_in[2];
    const float* anc0 = (const float*)d_in[3];
    const float* anc1 = (const float*)d_in[4];
    const float* anc2 = (const float*)d_in[5];
    float* out = (float*)d_out;

    // workspace: hist(8*2048) | cutb(8) | ccnt(8) | ckey(8*CAP) | cidx(8*CAP)
    unsigned* hist = (unsigned*)d_ws;
    unsigned* cutb = hist + 8 * NBIN1;
    unsigned* ccnt = cutb + 8;
    unsigned* ckey = ccnt + 8;
    unsigned* cidx = ckey + (size_t)8 * CAP;

    init_kernel<<<(NBIN1 * 8 + 16 + 255) / 256, 256, 0, stream>>>(hist);

    dim3 g(72, 3, 8);
    decode_pass<0><<<g, 256, 0, stream>>>(tip0, tip1, tip2, hist, cutb, ccnt, ckey, cidx);
    findcut_kernel<<<8, 256, 0, stream>>>(hist, cutb);
    decode_pass<1><<<g, 256, 0, stream>>>(tip0, tip1, tip2, hist, cutb, ccnt, ckey, cidx);
    nms_kernel<<<8, 512, 0, stream>>>(tip0, tip1, tip2, anc0, anc1, anc2,
                                      ckey, cidx, ccnt, out);
}

// Round 5
// 286.598 us; speedup vs baseline: 1.5712x; 1.0063x over previous
//
#include <hip/hip_runtime.h>
#include <stdint.h>

#define NUMA 3
#define NUMC 80
#define CAP  16384
#define KTOP 400
#define POST 100
#define NBIN1 2048
#define EQCAP 1024

__device__ __forceinline__ float sigmoidf_(float x) { return 1.0f / (1.0f + expf(-x)); }
__device__ __forceinline__ unsigned uminu(unsigned a, unsigned b) { return a < b ? a : b; }

// ---------------- init: zero hist + cutb + ccnt ----------------------------
__global__ void init_kernel(unsigned* __restrict__ p) {
    int i = blockIdx.x * blockDim.x + threadIdx.x;
    if (i < NBIN1 * 8 + 16) p[i] = 0;
}

// ---------------- score emit helper ----------------------------------------
template <int MODE>
__device__ __forceinline__ void emit_score(float sc, unsigned idx, unsigned cutkey,
        unsigned* lh, int b, unsigned* ccnt, unsigned* ckey, unsigned* cidx)
{
    unsigned key = __float_as_uint(sc);
    if (MODE == 0) {
        atomicAdd(&lh[key >> 19], 1u);
    } else {
        if (key >= cutkey) {
            unsigned pos = atomicAdd(&ccnt[b], 1u);
            if (pos < CAP) {
                ckey[(size_t)b * CAP + pos] = key;
                cidx[(size_t)b * CAP + pos] = idx;
            }
        }
    }
}

// ---------------- score passes: flat mapping, ~2 loads per thread ----------
// grid (10, 10, 24): x = hw-chunk (0-1: t0 scalar; 2-3: t1 float4; 4-9: t2
// float4), y = class-group (8 classes), z = b*3 + a. Per thread: 1 conf load
// + 8 class loads (straight-line, independent) + 8 or 32 scores. MLP comes
// from 8 resident waves/SIMD, not from a per-thread loop.
template <int MODE>
__global__ __launch_bounds__(256, 6) void score_pass(
        const float* __restrict__ t0, const float* __restrict__ t1,
        const float* __restrict__ t2,
        unsigned* __restrict__ hist, const unsigned* __restrict__ cutb,
        unsigned* __restrict__ ccnt, unsigned* __restrict__ ckey,
        unsigned* __restrict__ cidx)
{
    __shared__ unsigned lh[(MODE == 0) ? NBIN1 : 1];
    const int tid = threadIdx.x;
    if (MODE == 0) {
        for (int i = tid; i < NBIN1; i += 256) lh[i] = 0;
        __syncthreads();
    }
    const int ba = blockIdx.z;
    const int b = ba / 3, a = ba - 3 * b;
    const int c0 = blockIdx.y * 8;
    const int cx = blockIdx.x;

    unsigned cutkey = 0;
    if (MODE == 1) cutkey = cutb[b] << 19;

    if (cx < 2) {
        // ---- t0: HW=361, scalar ----
        const int hw = cx * 256 + tid;
        if (hw < 361) {
            const float* base = t0 + (size_t)(b * 255 + a * 85) * 361;
            float cr = base[4 * 361 + hw];
            const float* p0 = base + (size_t)(5 + c0) * 361 + hw;
            float x0 = p0[0 * 361], x1 = p0[1 * 361], x2 = p0[2 * 361], x3 = p0[3 * 361];
            float x4 = p0[4 * 361], x5 = p0[5 * 361], x6 = p0[6 * 361], x7 = p0[7 * 361];
            float cf = sigmoidf_(cr);
            unsigned ib = (unsigned)((hw * NUMA + a) * NUMC + c0);
            emit_score<MODE>(sigmoidf_(x0) * cf, ib + 0, cutkey, lh, b, ccnt, ckey, cidx);
            emit_score<MODE>(sigmoidf_(x1) * cf, ib + 1, cutkey, lh, b, ccnt, ckey, cidx);
            emit_score<MODE>(sigmoidf_(x2) * cf, ib + 2, cutkey, lh, b, ccnt, ckey, cidx);
            emit_score<MODE>(sigmoidf_(x3) * cf, ib + 3, cutkey, lh, b, ccnt, ckey, cidx);
            emit_score<MODE>(sigmoidf_(x4) * cf, ib + 4, cutkey, lh, b, ccnt, ckey, cidx);
            emit_score<MODE>(sigmoidf_(x5) * cf, ib + 5, cutkey, lh, b, ccnt, ckey, cidx);
            emit_score<MODE>(sigmoidf_(x6) * cf, ib + 6, cutkey, lh, b, ccnt, ckey, cidx);
            emit_score<MODE>(sigmoidf_(x7) * cf, ib + 7, cutkey, lh, b, ccnt, ckey, cidx);
        }
    } else {
        // ---- t1/t2: float4 ----
        const float* tip; int vHW, v, candOff;
        if (cx < 4) { tip = t1; vHW = 361;  v = (cx - 2) * 256 + tid; candOff = 86640; }
        else        { tip = t2; vHW = 1444; v = (cx - 4) * 256 + tid; candOff = 433200; }
        if (v < vHW) {
            const float4* bp = (const float4*)(tip + (size_t)(b * 255 + a * 85) * (size_t)(vHW * 4));
            float4 cv = bp[(size_t)4 * vHW + v];
            const float4* p0 = bp + (size_t)(5 + c0) * vHW + v;
            float4 s0 = p0[0 * (size_t)vHW], s1 = p0[1 * (size_t)vHW];
            float4 s2 = p0[2 * (size_t)vHW], s3 = p0[3 * (size_t)vHW];
            float4 s4 = p0[4 * (size_t)vHW], s5 = p0[5 * (size_t)vHW];
            float4 s6 = p0[6 * (size_t)vHW], s7 = p0[7 * (size_t)vHW];
            float cf0 = sigmoidf_(cv.x), cf1 = sigmoidf_(cv.y);
            float cf2 = sigmoidf_(cv.z), cf3 = sigmoidf_(cv.w);
            unsigned ib0 = (unsigned)(candOff + (v * 4 * NUMA + a) * NUMC + c0);
            #define EMIT4(S, U) do { \
                unsigned ib = ib0 + (U); \
                emit_score<MODE>(sigmoidf_((S).x) * cf0, ib,       cutkey, lh, b, ccnt, ckey, cidx); \
                emit_score<MODE>(sigmoidf_((S).y) * cf1, ib + 240, cutkey, lh, b, ccnt, ckey, cidx); \
                emit_score<MODE>(sigmoidf_((S).z) * cf2, ib + 480, cutkey, lh, b, ccnt, ckey, cidx); \
                emit_score<MODE>(sigmoidf_((S).w) * cf3, ib + 720, cutkey, lh, b, ccnt, ckey, cidx); \
            } while (0)
            EMIT4(s0, 0); EMIT4(s1, 1); EMIT4(s2, 2); EMIT4(s3, 3);
            EMIT4(s4, 4); EMIT4(s5, 5); EMIT4(s6, 6); EMIT4(s7, 7);
            #undef EMIT4
        }
    }

    if (MODE == 0) {
        __syncthreads();
        unsigned* gh = hist + b * NBIN1;
        for (int i = tid; i < NBIN1; i += 256) {
            unsigned v2 = lh[i];
            if (v2) atomicAdd(&gh[i], v2);
        }
    }
}

// ---------------- wave-parallel rank select over an LDS histogram ----------
__device__ __forceinline__ void wave_select(const unsigned* h, int nbins, unsigned rank,
                                            unsigned* resv, int tid)
{
    if (tid >= 64) return;
    const int lane = tid;
    const int cs = nbins >> 6;
    unsigned v = 0;
    for (int k = 0; k < cs; k++) {
        int off = (k + lane) & (cs - 1);
        v += h[lane * cs + off];
    }
    unsigned S = v;
    #pragma unroll
    for (int o = 1; o < 64; o <<= 1) {
        unsigned t = (unsigned)__shfl_down((int)S, o);
        if (lane + o < 64) S += t;
    }
    unsigned long long bm = __ballot(S >= rank);
    int C = 63 - __builtin_clzll(bm);
    unsigned SC = (unsigned)__builtin_amdgcn_readlane((int)S, C);
    unsigned vC = (unsigned)__builtin_amdgcn_readlane((int)v, C);
    unsigned rem = rank - (SC - vC);
    unsigned w = (lane < cs) ? h[C * cs + lane] : 0u;
    unsigned T = w;
    #pragma unroll
    for (int o = 1; o < 64; o <<= 1) {
        unsigned t = (unsigned)__shfl_down((int)T, o);
        if (lane + o < 64) T += t;
    }
    unsigned long long bm2 = __ballot((T >= rem) && (lane < cs));
    int B = 63 - __builtin_clzll(bm2);
    unsigned TB = (unsigned)__builtin_amdgcn_readlane((int)T, B);
    unsigned wB = (unsigned)__builtin_amdgcn_readlane((int)w, B);
    if (lane == 0) {
        resv[0] = (unsigned)(C * cs + B);
        resv[1] = rem - (TB - wB);
    }
}

// ---------------- find rank-400 bin per image ------------------------------
__global__ __launch_bounds__(256) void findcut_kernel(const unsigned* __restrict__ hist,
                                                      unsigned* __restrict__ cutb) {
    __shared__ unsigned h[NBIN1];
    __shared__ unsigned resv[2];
    int b = blockIdx.x;
    for (int i = threadIdx.x; i < NBIN1; i += 256) h[i] = hist[b * NBIN1 + i];
    __syncthreads();
    wave_select(h, NBIN1, KTOP, resv, threadIdx.x);
    __syncthreads();
    if (threadIdx.x == 0) cutb[b] = resv[0];
}

// ---------------- per-image: exact top-400, NMS, output --------------------
__global__ __launch_bounds__(512) void nms_kernel(
        const float* __restrict__ t0, const float* __restrict__ t1,
        const float* __restrict__ t2,
        const float* __restrict__ anc0, const float* __restrict__ anc1,
        const float* __restrict__ anc2,
        const unsigned* __restrict__ ckey, const unsigned* __restrict__ cidx,
        const unsigned* __restrict__ ccnt, float* __restrict__ out)
{
    const int b = blockIdx.x;
    const int tid = threadIdx.x;
    const int T = 512;

    __shared__ unsigned hist[4096];
    __shared__ unsigned resv[2];
    __shared__ unsigned selk[512], seli[512];
    __shared__ unsigned eqi[EQCAP];
    __shared__ float sx1[KTOP], sy1[KTOP], sx2[KTOP], sy2[KTOP], ssc[KTOP];
    __shared__ int   scid[KTOP];
    __shared__ unsigned long long maskS[KTOP * 7];
    __shared__ unsigned long long vkeep[7];
    __shared__ unsigned cnts[2];
    __shared__ float oid[POST], osc[POST], obb[POST * 4];

    const unsigned n = uminu(ccnt[b], (unsigned)CAP);
    const unsigned* ck = ckey + (size_t)b * CAP;
    const unsigned* ci = cidx + (size_t)b * CAP;

    // ---- Round 1: bits [30:19] ----
    for (int i = tid; i < NBIN1; i += T) hist[i] = 0;
    __syncthreads();
    for (unsigned i = tid; i < n; i += T) atomicAdd(&hist[ck[i] >> 19], 1u);
    __syncthreads();
    wave_select(hist, NBIN1, KTOP, resv, tid);
    __syncthreads();
    unsigned b1 = resv[0], r2 = resv[1];
    __syncthreads();

    // ---- Round 2: bits [18:7] ----
    for (int i = tid; i < 4096; i += T) hist[i] = 0;
    __syncthreads();
    for (unsigned i = tid; i < n; i += T) {
        unsigned k = ck[i];
        if ((k >> 19) == b1) atomicAdd(&hist[(k >> 7) & 0xFFFu], 1u);
    }
    __syncthreads();
    wave_select(hist, 4096, r2, resv, tid);
    __syncthreads();
    unsigned b2 = resv[0], r3 = resv[1];
    __syncthreads();

    // ---- Round 3: bits [6:0] ----
    for (int i = tid; i < 128; i += T) hist[i] = 0;
    __syncthreads();
    unsigned pref = (b1 << 12) | b2;
    for (unsigned i = tid; i < n; i += T) {
        unsigned k = ck[i];
        if ((k >> 7) == pref) atomicAdd(&hist[k & 127u], 1u);
    }
    __syncthreads();
    wave_select(hist, 128, r3, resv, tid);
    __syncthreads();
    unsigned b3 = resv[0], needEq = resv[1];
    unsigned K400 = (b1 << 19) | (b2 << 7) | b3;
    __syncthreads();

    // ---- compaction ----
    selk[tid] = 0u; seli[tid] = 0xFFFFFFFFu;
    for (int i = tid; i < EQCAP; i += T) eqi[i] = 0xFFFFFFFFu;
    if (tid == 0) { cnts[0] = 0; cnts[1] = 0; }
    __syncthreads();
    for (unsigned i = tid; i < n; i += T) {
        unsigned k = ck[i];
        if (k > K400) {
            unsigned p = atomicAdd(&cnts[0], 1u);
            if (p < KTOP) { selk[p] = k; seli[p] = ci[i]; }
        } else if (k == K400) {
            unsigned q = atomicAdd(&cnts[1], 1u);
            if (q < EQCAP) eqi[q] = ci[i];
        }
    }
    __syncthreads();
    unsigned selCnt = uminu(cnts[0], (unsigned)KTOP);
    unsigned eqN   = uminu(cnts[1], (unsigned)EQCAP);

    // ---- tie list: only sort if we must pick a strict subset ----
    if (eqN > needEq) {
        int P2 = 1; while ((unsigned)P2 < eqN) P2 <<= 1;
        for (int k2 = 2; k2 <= P2; k2 <<= 1) {
            for (int j = k2 >> 1; j > 0; j >>= 1) {
                __syncthreads();
                for (int i = tid; i < P2; i += T) {
                    int ixj = i ^ j;
                    if (ixj > i && ixj < P2) {
                        unsigned va = eqi[i], vb = eqi[ixj];
                        bool up = ((i & k2) == 0);
                        if (up ? (va > vb) : (va < vb)) { eqi[i] = vb; eqi[ixj] = va; }
                    }
                }
            }
        }
        __syncthreads();
    }
    for (unsigned t2v = tid; t2v < needEq; t2v += T) {
        unsigned p = selCnt + t2v;
        if (p < KTOP) { selk[p] = K400; seli[p] = eqi[t2v]; }
    }
    __syncthreads();

    // ---- bitonic sort 512 by (key desc, idx asc); j<64 passes in-wave ----
    for (int k2 = 2; k2 <= 512; k2 <<= 1) {
        int j = k2 >> 1;
        for (; j >= 64; j >>= 1) {
            __syncthreads();
            int i = tid, ixj = i ^ j;
            if (ixj > i) {
                unsigned ka = selk[i], kb = selk[ixj], ia = seli[i], ib = seli[ixj];
                bool before = (ka > kb) || (ka == kb && ia < ib);
                bool up = ((i & k2) == 0);
                if (up ? !before : before) {
                    selk[i] = kb; selk[ixj] = ka; seli[i] = ib; seli[ixj] = ia;
                }
            }
        }
        __syncthreads();
        for (; j > 0; j >>= 1) {
            int i = tid, ixj = i ^ j;
            if (ixj > i) {
                unsigned ka = selk[i], kb = selk[ixj], ia = seli[i], ib = seli[ixj];
                bool before = (ka > kb) || (ka == kb && ia < ib);
                bool up = ((i & k2) == 0);
                if (up ? !before : before) {
                    selk[i] = kb; selk[ixj] = ka; seli[i] = ib; seli[ixj] = ia;
                }
            }
        }
    }
    __syncthreads();

    // ---- gather + on-the-fly box decode for the 400 selected ----
    if (tid < KTOP) {
        unsigned idx = seli[tid];
        const float* tip; const float* anc; int HW, W, candOff; float strideF;
        if (idx < 86640u)       { tip = t0; anc = anc0; HW = 361;  W = 19; strideF = 32.f; candOff = 0; }
        else if (idx < 433200u) { tip = t1; anc = anc1; HW = 1444; W = 38; strideF = 16.f; candOff = 86640; }
        else                    { tip = t2; anc = anc2; HW = 5776; W = 76; strideF = 8.f;  candOff = 433200; }
        unsigned local = idx - (unsigned)candOff;
        int cls = (int)(local % NUMC);
        int nn  = (int)(local / NUMC);
        int a = nn % NUMA, hwl = nn / NUMA;
        const float* base = tip + (size_t)(b * 255 + a * 85) * HW + hwl;
        float tx = base[0];
        float ty = base[(size_t)HW];
        float tw = base[(size_t)2 * HW];
        float th = base[(size_t)3 * HW];
        float fx = (float)(hwl % W), fy = (float)(hwl / W);
        float cx = (sigmoidf_(tx) + fx) * strideF;
        float cy = (sigmoidf_(ty) + fy) * strideF;
        float hw_ = expf(tw) * anc[2 * a]     * 0.5f;
        float hh_ = expf(th) * anc[2 * a + 1] * 0.5f;
        sx1[tid] = cx - hw_; sy1[tid] = cy - hh_;
        sx2[tid] = cx + hw_; sy2[tid] = cy + hh_;
        ssc[tid] = __uint_as_float(selk[tid]);
        scid[tid] = cls;
    }
    __syncthreads();

    // ---- suppression bitmasks ----
    for (int p = tid; p < KTOP * 7; p += T) {
        int i = p / 7, w = p - i * 7;
        float x1i = sx1[i], y1i = sy1[i], x2i = sx2[i], y2i = sy2[i];
        float ai = fmaxf(x2i - x1i, 0.f) * fmaxf(y2i - y1i, 0.f);
        int cidI = scid[i];
        unsigned long long m = 0ull;
        int j0 = w * 64;
        int j1 = j0 + 64; if (j1 > KTOP) j1 = KTOP;
        int js = j0 > i + 1 ? j0 : i + 1;
        for (int j = js; j < j1; j++) {
            if (scid[j] != cidI) continue;
            float iw = fminf(x2i, sx2[j]) - fmaxf(x1i, sx1[j]);
            float ih = fminf(y2i, sy2[j]) - fmaxf(y1i, sy1[j]);
            iw = fmaxf(iw, 0.f); ih = fmaxf(ih, 0.f);
            float inter = iw * ih;
            float aj = fmaxf(sx2[j] - sx1[j], 0.f) * fmaxf(sy2[j] - sy1[j], 0.f);
            float iou = inter / (ai + aj - inter + 1e-12f);
            if (iou > 0.45f) m |= (1ull << (j - j0));
        }
        maskS[p] = m;
    }
    __syncthreads();

    // ---- greedy NMS: keep words in lanes 0..6; v_readlane broadcast -------
    if (tid < 64) {
        unsigned long long keep = 0ull;
        if (tid < 7) keep = (tid == 6) ? 0xFFFFull : ~0ull;
        unsigned long long m = (tid < 7) ? maskS[tid] : 0ull;
        for (int i = 0; i < KTOP; i++) {
            unsigned long long mn = (tid < 7 && i + 1 < KTOP) ? maskS[(i + 1) * 7 + tid] : 0ull;
            int w = i >> 6;
            unsigned klo = (unsigned)__builtin_amdgcn_readlane((int)(unsigned)(keep & 0xFFFFFFFFull), w);
            unsigned khi = (unsigned)__builtin_amdgcn_readlane((int)(unsigned)(keep >> 32), w);
            unsigned long long kw = ((unsigned long long)khi << 32) | klo;
            if ((kw >> (i & 63)) & 1ull) keep &= ~m;
            m = mn;
        }
        if (tid < 7) vkeep[tid] = keep;
    }
    __syncthreads();

    // ---- emit top-100, pad -1 ----
    if (tid < POST) { oid[tid] = -1.f; osc[tid] = -1.f; }
    if (tid < POST * 4) obb[tid] = -1.f;
    __syncthreads();
    if (tid < KTOP) {
        int w = tid >> 6, bp = tid & 63;
        unsigned long long kw = vkeep[w];
        if ((kw >> bp) & 1ull) {
            int r = 0;
            for (int q = 0; q < w; q++) r += __popcll(vkeep[q]);
            r += __popcll(kw & ((1ull << bp) - 1ull));
            if (r < POST) {
                oid[r] = (float)scid[tid];
                osc[r] = ssc[tid];
                obb[r * 4 + 0] = sx1[tid];
                obb[r * 4 + 1] = sy1[tid];
                obb[r * 4 + 2] = sx2[tid];
                obb[r * 4 + 3] = sy2[tid];
            }
        }
    }
    __syncthreads();
    if (tid < POST) {
        out[b * POST + tid]       = oid[tid];
        out[800 + b * POST + tid] = osc[tid];
    }
    if (tid < POST * 4) out[1600 + b * POST * 4 + tid] = obb[tid];
}

// ---------------------------------------------------------------------------
extern "C" void kernel_launch(void* const* d_in, const int* in_sizes, int n_in,
                              void* d_out, int out_size, void* d_ws, size_t ws_size,
                              hipStream_t stream)
{
    const float* tip0 = (const float*)d_in[0];
    const float* tip1 = (const float*)d_in[1];
    const float* tip2 = (const float*)d_in[2];
    const float* anc0 = (const float*)d_in[3];
    const float* anc1 = (const float*)d_in[4];
    const float* anc2 = (const float*)d_in[5];
    float* out = (float*)d_out;

    // workspace: hist(8*2048) | cutb(8) | ccnt(8) | ckey(8*CAP) | cidx(8*CAP)
    unsigned* hist = (unsigned*)d_ws;
    unsigned* cutb = hist + 8 * NBIN1;
    unsigned* ccnt = cutb + 8;
    unsigned* ckey = ccnt + 8;
    unsigned* cidx = ckey + (size_t)8 * CAP;

    init_kernel<<<(NBIN1 * 8 + 16 + 255) / 256, 256, 0, stream>>>(hist);

    dim3 g(10, 10, 24);
    score_pass<0><<<g, 256, 0, stream>>>(tip0, tip1, tip2, hist, cutb, ccnt, ckey, cidx);
    findcut_kernel<<<8, 256, 0, stream>>>(hist, cutb);
    score_pass<1><<<g, 256, 0, stream>>>(tip0, tip1, tip2, hist, cutb, ccnt, ckey, cidx);
    nms_kernel<<<8, 512, 0, stream>>>(tip0, tip1, tip2, anc0, anc1, anc2,
                                      ckey, cidx, ccnt, out);
}